// Round 4
// baseline (1725.625 us; speedup 1.0000x reference)
//
#include <hip/hip_runtime.h>

typedef _Float16 h2 __attribute__((ext_vector_type(2)));

#define MAT_N 256
#define MAT_ELEMS (MAT_N * MAT_N)
#define NUM_ITERS 20

// ---- cross-lane DPP add (VALU pipe, no LDS) -----------------------------
template<int CTRL>
__device__ __forceinline__ float dpp_add(float x) {
    int i = __builtin_bit_cast(int, x);
    int r = __builtin_amdgcn_update_dpp(i, i, CTRL, 0xF, 0xF, true);
    return x + __builtin_bit_cast(float, r);
}
// Reduce across the 16 lanes sharing a row-group (DPP only, no ds_swizzle).
__device__ __forceinline__ float row16_reduce(float x) {
    x = dpp_add<0xB1>(x);    // quad_perm xor1
    x = dpp_add<0x4E>(x);    // quad_perm xor2
    x = dpp_add<0x141>(x);   // row_half_mirror (cross-quad within 8)
    x = dpp_add<0x140>(x);   // row_mirror (cross-half within 16)
    return x;
}

__device__ __forceinline__ float dot2(h2 a, h2 b, float c) {
    return __builtin_amdgcn_fdot2(a, b, c, false);
}

// 512-thread block per matrix; 2 blocks/CU resident (<=128 VGPR).
// Thread (R = tid>>4, C = tid&15) owns rows 8R..8R+7 and cols {4C..4C+3}+64d,
// d=0..3 (16 cols), f16-packed: qp[i][2d+m] = cols (4C+2m+64d, 4C+2m+1+64d).
__global__ __launch_bounds__(512, 4) void sinkhorn_kernel(
        const float* __restrict__ in, float* __restrict__ out) {
    const int tid = threadIdx.x;
    const int C = tid & 15;    // col-lane
    const int R = tid >> 4;    // row-group 0..31

    __shared__ __align__(16) float Q1[32][260];  // col partials, 33.3 KB
    __shared__ __align__(16) float Vc[256];      // col reciprocals

    const size_t base = (size_t)blockIdx.x * MAT_ELEMS;
    const float4* __restrict__ in4 = (const float4*)(in + base);
    float4* __restrict__ out4 = (float4*)(out + base);

    // ---- load + exp -> f16 packed (64 VGPRs of state) ----
    h2 qp[8][8];
    #pragma unroll
    for (int i = 0; i < 8; ++i) {
        #pragma unroll
        for (int d = 0; d < 4; ++d) {
            float4 t = in4[(8 * R + i) * 64 + C + 16 * d];
            h2 a, b;
            a.x = (_Float16)__expf(t.x); a.y = (_Float16)__expf(t.y);
            b.x = (_Float16)__expf(t.z); b.y = (_Float16)__expf(t.w);
            qp[i][2 * d] = a; qp[i][2 * d + 1] = b;
        }
    }

    h2 vp[8];
    {
        h2 one; one.x = (_Float16)1.f; one.y = (_Float16)1.f;
        #pragma unroll
        for (int j = 0; j < 8; ++j) vp[j] = one;
    }
    float u[8];

    #pragma unroll 1
    for (int it = 0; it < NUM_ITERS; ++it) {
        // ---- row phase: u = 1/(M v). dot2 + pure-DPP 16-lane reduce ----
        #pragma unroll
        for (int i = 0; i < 8; ++i) {
            float s = dot2(qp[i][0], vp[0], 0.f);
            #pragma unroll
            for (int jj = 1; jj < 8; ++jj) s = dot2(qp[i][jj], vp[jj], s);
            s = row16_reduce(s);
            u[i] = __builtin_amdgcn_rcpf(s);
        }

        // ---- col phase: v = 1/(M^T u), f32 accumulation (fma_mix) ----
        float cs[16];
        #pragma unroll
        for (int c = 0; c < 16; ++c) cs[c] = 0.f;
        #pragma unroll
        for (int i = 0; i < 8; ++i) {
            const float ui = u[i];
            #pragma unroll
            for (int jj = 0; jj < 8; ++jj) {
                cs[2 * jj]     = fmaf((float)qp[i][jj].x, ui, cs[2 * jj]);
                cs[2 * jj + 1] = fmaf((float)qp[i][jj].y, ui, cs[2 * jj + 1]);
            }
        }
        // cs[4d..4d+3] = cols 4C+64d..4C+3+64d  -> contiguous float4
        #pragma unroll
        for (int d = 0; d < 4; ++d) {
            *(float4*)&Q1[R][4 * C + 64 * d] =
                make_float4(cs[4 * d], cs[4 * d + 1], cs[4 * d + 2], cs[4 * d + 3]);
        }
        __syncthreads();

        {   // stage 2: 2 threads per column (rows 0..15 / 16..31), DPP pair-combine
            const int col = tid >> 1;
            const int r0 = (tid & 1) * 16;
            float a0 = 0.f, a1 = 0.f, a2 = 0.f, a3 = 0.f;
            #pragma unroll
            for (int k = 0; k < 16; k += 4) {
                a0 += Q1[r0 + k][col];
                a1 += Q1[r0 + k + 1][col];
                a2 += Q1[r0 + k + 2][col];
                a3 += Q1[r0 + k + 3][col];
            }
            float s = (a0 + a1) + (a2 + a3);
            s = dpp_add<0xB1>(s);            // lanes 2c <-> 2c+1
            if ((tid & 1) == 0) Vc[col] = __builtin_amdgcn_rcpf(s);
        }
        __syncthreads();

        // ---- reload v as f16 pairs ----
        #pragma unroll
        for (int d = 0; d < 4; ++d) {
            float4 a = *(const float4*)&Vc[4 * C + 64 * d];
            h2 t0, t1;
            t0.x = (_Float16)a.x; t0.y = (_Float16)a.y;
            t1.x = (_Float16)a.z; t1.y = (_Float16)a.w;
            vp[2 * d] = t0; vp[2 * d + 1] = t1;
        }
    }

    // ---- store: out = u_i * q_ij * v_j (f32) ----
    #pragma unroll
    for (int i = 0; i < 8; ++i) {
        const float s = u[i];
        #pragma unroll
        for (int d = 0; d < 4; ++d) {
            float4 a = *(const float4*)&Vc[4 * C + 64 * d];
            float4 o;
            o.x = (float)qp[i][2 * d].x     * (s * a.x);
            o.y = (float)qp[i][2 * d].y     * (s * a.y);
            o.z = (float)qp[i][2 * d + 1].x * (s * a.z);
            o.w = (float)qp[i][2 * d + 1].y * (s * a.w);
            out4[(8 * R + i) * 64 + C + 16 * d] = o;
        }
    }
}

extern "C" void kernel_launch(void* const* d_in, const int* in_sizes, int n_in,
                              void* d_out, int out_size, void* d_ws, size_t ws_size,
                              hipStream_t stream) {
    const float* in = (const float*)d_in[0];
    float* out = (float*)d_out;
    const int nmat = in_sizes[0] / MAT_ELEMS;  // 2048
    sinkhorn_kernel<<<nmat, 512, 0, stream>>>(in, out);
}

// Round 5
// 349.618 us; speedup vs baseline: 4.9357x; 4.9357x over previous
//
#include <hip/hip_runtime.h>

typedef _Float16 h2 __attribute__((ext_vector_type(2)));

#define MAT_N 256
#define MAT_ELEMS (MAT_N * MAT_N)
#define NUM_ITERS 20

// ---- cross-lane DPP add (VALU pipe, no LDS) -----------------------------
template<int CTRL>
__device__ __forceinline__ float dpp_add(float x) {
    int i = __builtin_bit_cast(int, x);
    int r = __builtin_amdgcn_update_dpp(i, i, CTRL, 0xF, 0xF, true);
    return x + __builtin_bit_cast(float, r);
}
// Reduce across the 16 lanes sharing a row-group (DPP only).
__device__ __forceinline__ float row16_reduce(float x) {
    x = dpp_add<0xB1>(x);    // quad_perm xor1
    x = dpp_add<0x4E>(x);    // quad_perm xor2
    x = dpp_add<0x141>(x);   // row_half_mirror (xor4-equivalent)
    x = dpp_add<0x140>(x);   // row_mirror (xor8-equivalent)
    return x;
}

__device__ __forceinline__ float dot2(h2 a, h2 b, float c) {
    return __builtin_amdgcn_fdot2(a, b, c, false);
}

// 512-thread block per matrix; target 2 blocks/CU.
// Thread (R = tid>>4, C = tid&15) owns rows 8R..8R+7 and cols {4C..4C+3}+64d,
// d=0..3 (16 cols), f16-packed: qp[i][2d+m] = cols (4C+2m+64d, 4C+2m+1+64d).
// NOTE: empirical hipcc rule on gfx950 (rounds 2-4): arch-VGPR cap = 256/arg2.
// arg2=2 -> 128 arch VGPRs; live state ~100 -> no spill, 4 waves/SIMD.
__global__ __launch_bounds__(512, 2) void sinkhorn_kernel(
        const float* __restrict__ in, float* __restrict__ out) {
    const int tid = threadIdx.x;
    const int C = tid & 15;    // col-lane
    const int R = tid >> 4;    // row-group 0..31

    __shared__ __align__(16) float Q1[32][260];  // col partials, 33.3 KB
    __shared__ __align__(16) float Vc[256];      // col reciprocals

    const size_t base = (size_t)blockIdx.x * MAT_ELEMS;
    const float4* __restrict__ in4 = (const float4*)(in + base);
    float4* __restrict__ out4 = (float4*)(out + base);

    // ---- load + exp -> f16 packed (64 VGPRs of state) ----
    h2 qp[8][8];
    #pragma unroll
    for (int i = 0; i < 8; ++i) {
        #pragma unroll
        for (int d = 0; d < 4; ++d) {
            float4 t = in4[(8 * R + i) * 64 + C + 16 * d];
            h2 a, b;
            a.x = (_Float16)__expf(t.x); a.y = (_Float16)__expf(t.y);
            b.x = (_Float16)__expf(t.z); b.y = (_Float16)__expf(t.w);
            qp[i][2 * d] = a; qp[i][2 * d + 1] = b;
        }
    }

    h2 vp[8];
    {
        h2 one; one.x = (_Float16)1.f; one.y = (_Float16)1.f;
        #pragma unroll
        for (int j = 0; j < 8; ++j) vp[j] = one;
    }
    float u[8];

    #pragma unroll 1
    for (int it = 0; it < NUM_ITERS; ++it) {
        // ---- row phase: u = 1/(M v). dot2 + pure-DPP 16-lane reduce ----
        #pragma unroll
        for (int i = 0; i < 8; ++i) {
            float s = dot2(qp[i][0], vp[0], 0.f);
            #pragma unroll
            for (int jj = 1; jj < 8; ++jj) s = dot2(qp[i][jj], vp[jj], s);
            s = row16_reduce(s);
            u[i] = __builtin_amdgcn_rcpf(s);
        }

        // ---- col phase: v = 1/(M^T u), f32 accumulation, per-d groups ----
        // (4 live accumulators at a time keeps peak VGPR pressure low)
        #pragma unroll
        for (int d = 0; d < 4; ++d) {
            float c0 = 0.f, c1 = 0.f, c2 = 0.f, c3 = 0.f;
            #pragma unroll
            for (int i = 0; i < 8; ++i) {
                const float ui = u[i];
                c0 = fmaf((float)qp[i][2 * d].x,     ui, c0);
                c1 = fmaf((float)qp[i][2 * d].y,     ui, c1);
                c2 = fmaf((float)qp[i][2 * d + 1].x, ui, c2);
                c3 = fmaf((float)qp[i][2 * d + 1].y, ui, c3);
            }
            *(float4*)&Q1[R][4 * C + 64 * d] = make_float4(c0, c1, c2, c3);
        }
        __syncthreads();

        {   // stage 2: 2 threads per column (rows 0..15 / 16..31), DPP pair-combine
            const int col = tid >> 1;
            const int r0 = (tid & 1) * 16;
            float a0 = 0.f, a1 = 0.f, a2 = 0.f, a3 = 0.f;
            #pragma unroll
            for (int k = 0; k < 16; k += 4) {
                a0 += Q1[r0 + k][col];
                a1 += Q1[r0 + k + 1][col];
                a2 += Q1[r0 + k + 2][col];
                a3 += Q1[r0 + k + 3][col];
            }
            float s = (a0 + a1) + (a2 + a3);
            s = dpp_add<0xB1>(s);            // lanes 2c <-> 2c+1
            if ((tid & 1) == 0) Vc[col] = __builtin_amdgcn_rcpf(s);
        }
        __syncthreads();

        // ---- reload v as f16 pairs ----
        #pragma unroll
        for (int d = 0; d < 4; ++d) {
            float4 a = *(const float4*)&Vc[4 * C + 64 * d];
            h2 t0, t1;
            t0.x = (_Float16)a.x; t0.y = (_Float16)a.y;
            t1.x = (_Float16)a.z; t1.y = (_Float16)a.w;
            vp[2 * d] = t0; vp[2 * d + 1] = t1;
        }
    }

    // ---- store: out = u_i * q_ij * v_j (f32, v from Vc) ----
    #pragma unroll
    for (int i = 0; i < 8; ++i) {
        const float s = u[i];
        #pragma unroll
        for (int d = 0; d < 4; ++d) {
            float4 a = *(const float4*)&Vc[4 * C + 64 * d];
            float4 o;
            o.x = (float)qp[i][2 * d].x     * (s * a.x);
            o.y = (float)qp[i][2 * d].y     * (s * a.y);
            o.z = (float)qp[i][2 * d + 1].x * (s * a.z);
            o.w = (float)qp[i][2 * d + 1].y * (s * a.w);
            out4[(8 * R + i) * 64 + C + 16 * d] = o;
        }
    }
}

extern "C" void kernel_launch(void* const* d_in, const int* in_sizes, int n_in,
                              void* d_out, int out_size, void* d_ws, size_t ws_size,
                              hipStream_t stream) {
    const float* in = (const float*)d_in[0];
    float* out = (float*)d_out;
    const int nmat = in_sizes[0] / MAT_ELEMS;  // 2048
    sinkhorn_kernel<<<nmat, 512, 0, stream>>>(in, out);
}

// Round 6
// 254.688 us; speedup vs baseline: 6.7755x; 1.3727x over previous
//
#include <hip/hip_runtime.h>

typedef _Float16 h2 __attribute__((ext_vector_type(2)));

#define MAT_N 256
#define MAT_ELEMS (MAT_N * MAT_N)
#define NUM_ITERS 20

// ---- cross-lane DPP helpers (VALU pipe, no LDS) -------------------------
template<int CTRL>
__device__ __forceinline__ float dpp_add(float x) {
    int i = __builtin_bit_cast(int, x);
    int r = __builtin_amdgcn_update_dpp(i, i, CTRL, 0xF, 0xF, true);
    return x + __builtin_bit_cast(float, r);
}
template<int CTRL>
__device__ __forceinline__ float dpp_mov(float x) {
    int i = __builtin_bit_cast(int, x);
    int r = __builtin_amdgcn_update_dpp(i, i, CTRL, 0xF, 0xF, true);
    return __builtin_bit_cast(float, r);
}
// Reduce across the 16 lanes sharing a row-group (DPP only).
__device__ __forceinline__ float row16_reduce(float x) {
    x = dpp_add<0xB1>(x);    // quad_perm xor1
    x = dpp_add<0x4E>(x);    // quad_perm xor2
    x = dpp_add<0x141>(x);   // row_half_mirror (xor4)
    x = dpp_add<0x140>(x);   // row_mirror (xor8)
    return x;
}

__device__ __forceinline__ float dot2(h2 a, h2 b, float c) {
    return __builtin_amdgcn_fdot2(a, b, c, false);
}

// 512-thread block per matrix; 2 blocks/CU (empirical: launch_bounds arg2=2
// -> 128 arch-VGPR cap on gfx950; live state ~105 -> no spill).
// Thread (R = tid>>4, C = tid&15) owns rows 8R..8R+7 and cols {4C..4C+3}+64d,
// d=0..3, f16-packed: qp[i][2d+m] = cols (4C+2m+64d, 4C+2m+1+64d).
__global__ __launch_bounds__(512, 2) void sinkhorn_kernel(
        const float* __restrict__ in, float* __restrict__ out) {
    const int tid = threadIdx.x;
    const int C = tid & 15;    // col-lane
    const int R = tid >> 4;    // row-group 0..31

    __shared__ __align__(16) float Q1[32][260];  // col partials (f32), 33.3 KB
    __shared__ __align__(4)  h2    Vch[128];     // packed col reciprocals (f16)

    const size_t base = (size_t)blockIdx.x * MAT_ELEMS;
    const float4* __restrict__ in4 = (const float4*)(in + base);
    float4* __restrict__ out4 = (float4*)(out + base);

    // ---- load + exp -> f16 packed (64 VGPRs of state) ----
    h2 qp[8][8];
    #pragma unroll
    for (int i = 0; i < 8; ++i) {
        #pragma unroll
        for (int d = 0; d < 4; ++d) {
            float4 t = in4[(8 * R + i) * 64 + C + 16 * d];
            h2 a, b;
            a.x = (_Float16)__expf(t.x); a.y = (_Float16)__expf(t.y);
            b.x = (_Float16)__expf(t.z); b.y = (_Float16)__expf(t.w);
            qp[i][2 * d] = a; qp[i][2 * d + 1] = b;
        }
    }

    h2 vp[8];
    {
        h2 one; one.x = (_Float16)1.f; one.y = (_Float16)1.f;
        #pragma unroll
        for (int j = 0; j < 8; ++j) vp[j] = one;
    }
    float u[8];

    #pragma unroll 1
    for (int it = 0; it < NUM_ITERS; ++it) {
        // ---- row phase: u = 1/(M v). dot2 + pure-DPP 16-lane reduce ----
        #pragma unroll
        for (int i = 0; i < 8; ++i) {
            float s = dot2(qp[i][0], vp[0], 0.f);
            #pragma unroll
            for (int jj = 1; jj < 8; ++jj) s = dot2(qp[i][jj], vp[jj], s);
            s = row16_reduce(s);
            u[i] = __builtin_amdgcn_rcpf(s);
        }

        // ---- col phase: packed-f16 accumulation (v_pk_fma_f16) ----
        h2 ca[8];
        {
            h2 z; z.x = (_Float16)0.f; z.y = (_Float16)0.f;
            #pragma unroll
            for (int p = 0; p < 8; ++p) ca[p] = z;
        }
        #pragma unroll
        for (int i = 0; i < 8; ++i) {
            const _Float16 uh = (_Float16)u[i];
            h2 ub; ub.x = uh; ub.y = uh;
            #pragma unroll
            for (int p = 0; p < 8; ++p)
                ca[p] = __builtin_elementwise_fma(qp[i][p], ub, ca[p]);
        }
        // unpack to f32 once, write float4 partials
        #pragma unroll
        for (int d = 0; d < 4; ++d) {
            float4 cv;
            cv.x = (float)ca[2 * d].x;     cv.y = (float)ca[2 * d].y;
            cv.z = (float)ca[2 * d + 1].x; cv.w = (float)ca[2 * d + 1].y;
            *(float4*)&Q1[R][4 * C + 64 * d] = cv;
        }
        __syncthreads();

        {   // stage 2: 2 threads per column (f32), emit packed-f16 reciprocals
            const int col = tid >> 1;
            const int r0 = (tid & 1) * 16;
            float a0 = 0.f, a1 = 0.f, a2 = 0.f, a3 = 0.f;
            #pragma unroll
            for (int k = 0; k < 16; k += 4) {
                a0 += Q1[r0 + k][col];
                a1 += Q1[r0 + k + 1][col];
                a2 += Q1[r0 + k + 2][col];
                a3 += Q1[r0 + k + 3][col];
            }
            float s = (a0 + a1) + (a2 + a3);
            s = dpp_add<0xB1>(s);                    // pair-combine: full colsum
            float rcp = __builtin_amdgcn_rcpf(s);    // col (tid>>1)
            float rcp2 = dpp_mov<0x4E>(rcp);         // fetch col (tid>>1)+1 from lane^2
            if ((tid & 3) == 0) {
                h2 pk; pk.x = (_Float16)rcp; pk.y = (_Float16)rcp2;
                Vch[tid >> 2] = pk;                  // col-pair (tid>>2)
            }
        }
        __syncthreads();

        // ---- reload v: 2 consecutive h2 per d (b64 reads, no cvt) ----
        #pragma unroll
        for (int d = 0; d < 4; ++d) {
            vp[2 * d]     = Vch[2 * C + 32 * d];
            vp[2 * d + 1] = Vch[2 * C + 32 * d + 1];
        }
    }

    // ---- store: out = u_i * q_ij * v_j (v from registers, cvt once) ----
    float vf[16];
    #pragma unroll
    for (int p = 0; p < 8; ++p) {
        vf[2 * p]     = (float)vp[p].x;
        vf[2 * p + 1] = (float)vp[p].y;
    }
    #pragma unroll
    for (int i = 0; i < 8; ++i) {
        const float s = u[i];
        #pragma unroll
        for (int d = 0; d < 4; ++d) {
            float4 o;
            o.x = (float)qp[i][2 * d].x     * (s * vf[4 * d]);
            o.y = (float)qp[i][2 * d].y     * (s * vf[4 * d + 1]);
            o.z = (float)qp[i][2 * d + 1].x * (s * vf[4 * d + 2]);
            o.w = (float)qp[i][2 * d + 1].y * (s * vf[4 * d + 3]);
            out4[(8 * R + i) * 64 + C + 16 * d] = o;
        }
    }
}

extern "C" void kernel_launch(void* const* d_in, const int* in_sizes, int n_in,
                              void* d_out, int out_size, void* d_ws, size_t ws_size,
                              hipStream_t stream) {
    const float* in = (const float*)d_in[0];
    float* out = (float*)d_out;
    const int nmat = in_sizes[0] / MAT_ELEMS;  // 2048
    sinkhorn_kernel<<<nmat, 512, 0, stream>>>(in, out);
}